// Round 5
// baseline (208.832 us; speedup 1.0000x reference)
//
#include <hip/hip_runtime.h>
#include <hip/hip_bf16.h>

#define Bq 128
#define Tq 4096
#define Nq 32
#define SEGL 64
#define NSEG 64
#define BURN 16
#define TRIPB 15         // BURN-1
#define UNR 4
#define NBLK 20          // UNR*NBLK = 80 >= 79 max steps
#define LOG2E 1.4426950408889634f

typedef float v2f __attribute__((ext_vector_type(2)));
typedef unsigned short u16;

__device__ __forceinline__ unsigned cvt_pk_bf16(float lo, float hi) {
  unsigned r;
  asm("v_cvt_pk_bf16_f32 %0, %1, %2" : "=v"(r) : "v"(lo), "v"(hi));
  return r;
}

// 4 chains per 64-thread block (one wave), 16 lanes/chain, 2 output cols/lane.
// State = 32 bf16 (16 dwords) per chain in LDS; each lane reads all 16 dwords
// (4 x b128; 16-lane broadcast free, cross-chain 2-way alias free) and MACs
// its 2 columns via unpack + v_pk_fma_f32. 16384 chains / 4096 waves = 4/SIMD
// (the TLP r4 lost). Renorm: once per 4-step block, scalar 2^-e from the
// previous step's first state dword (uniform per chain; rows carry arbitrary
// power-of-2 scale — dice renormalizes per row, so no scale arrays, no logZ).
extern "C" __global__ void __launch_bounds__(64, 4)
crf_chain_kernel(const float* __restrict__ pot, const int* __restrict__ lengths,
                 const float* __restrict__ trans,
                 u16* __restrict__ eaF, u16* __restrict__ eaB,
                 float* __restrict__ iacc) {
  __shared__ unsigned xbuf[4][16];
  const int tid = threadIdx.x;
  if (blockIdx.x < 2) iacc[blockIdx.x * 64 + tid] = 0.f;  // zero dice accumulators

  const int cslot = tid >> 4;
  const int sub = tid & 15;
  const int oc = sub << 1;              // output columns oc, oc+1
  const int cid = (blockIdx.x << 2) + cslot;
  const int b = cid >> 7;
  const int dir = (cid >> 6) & 1;       // 0 fwd, 1 bwd (uniform per block)
  const int s = cid & 63;
  const int len = lengths[b];
  const int sL = s * SEGL;
  const bool active = (sL < len);
  if (!__ballot(active)) return;

  const int lenm1 = len - 1;
  const int end = min(sL + SEGL, len) - 1;   // inclusive last row of segment
  const int t1 = min(lenm1, end + BURN);     // bwd init row (beta == 1 there)
  const int dstep = dir ? -1 : 1;
  const int cst = dir ? (end + BURN) : ((s == 0) ? (1 - TRIPB) : (sL - TRIPB));
  const int skip = dir ? (end + BURN - t1) : ((s == 0) ? TRIPB : 0);
  const int wlo = sL;
  const int whi = dir ? min(end, t1) : end;
  const unsigned uspan = (unsigned)(whi - wlo);

  // eT pairs over row-index pairs (2k,2k+1): fwd col j of exp(trans); bwd row i.
  v2f eTa[16], eTb[16];
#pragma unroll
  for (int k = 0; k < 16; ++k) {
    const int i0 = 2 * k, i1 = 2 * k + 1;
    float a0 = dir ? trans[oc * Nq + i0] : trans[i0 * Nq + oc];
    float a1 = dir ? trans[oc * Nq + i1] : trans[i1 * Nq + oc];
    float c0 = dir ? trans[(oc + 1) * Nq + i0] : trans[i0 * Nq + oc + 1];
    float c1 = dir ? trans[(oc + 1) * Nq + i1] : trans[i1 * Nq + oc + 1];
    eTa[k].x = exp2f(a0 * LOG2E); eTa[k].y = exp2f(a1 * LOG2E);
    eTb[k].x = exp2f(c0 * LOG2E); eTb[k].y = exp2f(c1 * LOG2E);
  }

  const float* pb = pot + (size_t)b * Tq * Nq;
  float raw0, raw1;
  if (dir) { raw0 = 1.f; raw1 = 1.f; }
  else {
    const int rinit = (s == 0) ? 0 : (sL - BURN);
    raw0 = exp2f(pb[rinit * Nq + oc] * LOG2E);
    raw1 = exp2f(pb[rinit * Nq + oc + 1] * LOG2E);
  }
  // Init rows are produced by held-state steps inside the window logic; no
  // explicit init stores needed (row 0 at g=TRIPB-? and bwd row t1 at g=skip-1).
  int r = cst - dir;                   // row written at the first step
  int cb = cst;                        // pot row consumed at step g = cb+dstep*g
  u16* outp = (dir ? eaB : eaF) + (size_t)b * Tq * Nq + oc + (ptrdiff_t)r * Nq;
  unsigned lb0 = 0x3f80u;              // low bf16 = 1.0 → first-block corr = 1

  v2f pn[UNR];
#pragma unroll
  for (int k = 0; k < UNR; ++k) {
    int cc = min(max(cst + dstep * k, 0), lenm1);
    pn[k] = *(const v2f*)(pb + cc * Nq + oc);
  }

#pragma unroll 1
  for (int blk = 0; blk < NBLK; ++blk) {
    {  // once-per-block power-of-2 renorm (uniform per chain, scale-invariant)
      int ebits = (int)((lb0 << 16) & 0x7f800000u);
      float corr = __int_as_float(0x7f000000 - ebits);
      raw0 *= corr; raw1 *= corr;
    }
    v2f pc[UNR];
#pragma unroll
    for (int k = 0; k < UNR; ++k) pc[k] = pn[k];
#pragma unroll
    for (int k = 0; k < UNR; ++k) {
      int cc = min(max(cb + dstep * (k + UNR), 0), lenm1);
      pn[k] = *(const v2f*)(pb + cc * Nq + oc);
    }
    const int g0 = blk * UNR;
#pragma unroll
    for (int k = 0; k < UNR; ++k) {
      float ep0 = exp2f(pc[k].x * LOG2E);
      float ep1 = exp2f(pc[k].y * LOG2E);
      float w0 = dir ? raw0 * ep0 : raw0;
      float w1 = dir ? raw1 * ep1 : raw1;
      xbuf[cslot][sub] = cvt_pk_bf16(w0, w1);
      const uint4* xb4 = (const uint4*)(&xbuf[cslot][0]);
      uint4 B0 = xb4[0], B1 = xb4[1], B2 = xb4[2], B3 = xb4[3];
      lb0 = B0.x;
      v2f a0 = 0.f, a1 = 0.f, d0 = 0.f, d1 = 0.f;
#define ACC(dw, p, A, D) { v2f xp; \
      xp.x = __uint_as_float((dw) << 16); \
      xp.y = __uint_as_float((dw) & 0xffff0000u); \
      A += xp * eTa[p]; D += xp * eTb[p]; }
      ACC(B0.x, 0, a0, d0) ACC(B0.y, 1, a1, d1) ACC(B0.z, 2, a0, d0) ACC(B0.w, 3, a1, d1)
      ACC(B1.x, 4, a0, d0) ACC(B1.y, 5, a1, d1) ACC(B1.z, 6, a0, d0) ACC(B1.w, 7, a1, d1)
      ACC(B2.x, 8, a0, d0) ACC(B2.y, 9, a1, d1) ACC(B2.z,10, a0, d0) ACC(B2.w,11, a1, d1)
      ACC(B3.x,12, a0, d0) ACC(B3.y,13, a1, d1) ACC(B3.z,14, a0, d0) ACC(B3.w,15, a1, d1)
#undef ACC
      v2f sa = a0 + a1, sd = d0 + d1;
      float s0 = sa.x + sa.y, s1 = sd.x + sd.y;
      float n0 = dir ? s0 : s0 * ep0;
      float n1 = dir ? s1 : s1 * ep1;
      const bool upd = (g0 + k) >= skip;
      raw0 = upd ? n0 : raw0;
      raw1 = upd ? n1 : raw1;
      if (active && (unsigned)(r - wlo) <= uspan)
        *(unsigned*)outp = cvt_pk_bf16(raw0, raw1);
      outp += dstep * Nq;
      r += dstep;
    }
    cb += dstep * UNR;
  }
}

// One THREAD per position; 2048 blocks. p_t[y]/sum via per-row normalization.
extern "C" __global__ void __launch_bounds__(256)
dice_kernel(const u16* __restrict__ eaF, const u16* __restrict__ eaB,
            const int* __restrict__ y, const int* __restrict__ lengths,
            float* __restrict__ iacc) {
  const int b = blockIdx.x >> 4;
  const int q = blockIdx.x & 15;
  const int len = lengths[b];
  if (q * 256 >= len) return;
  const int t = q * 256 + threadIdx.x;
  float I = 0.f;
  if (t < len) {
    const size_t base = ((size_t)b * Tq + t) * Nq;
    const uint4* a4 = (const uint4*)(eaF + base);
    const uint4* b4 = (const uint4*)(eaB + base);
    float c0 = 0.f, c1 = 0.f, c2 = 0.f, c3 = 0.f;
#pragma unroll
    for (int w = 0; w < 4; ++w) {
      uint4 ua = a4[w], ub = b4[w];
      c0 = fmaf(__uint_as_float(ua.x << 16), __uint_as_float(ub.x << 16), c0);
      c1 = fmaf(__uint_as_float(ua.x & 0xffff0000u), __uint_as_float(ub.x & 0xffff0000u), c1);
      c2 = fmaf(__uint_as_float(ua.y << 16), __uint_as_float(ub.y << 16), c2);
      c3 = fmaf(__uint_as_float(ua.y & 0xffff0000u), __uint_as_float(ub.y & 0xffff0000u), c3);
      c0 = fmaf(__uint_as_float(ua.z << 16), __uint_as_float(ub.z << 16), c0);
      c1 = fmaf(__uint_as_float(ua.z & 0xffff0000u), __uint_as_float(ub.z & 0xffff0000u), c1);
      c2 = fmaf(__uint_as_float(ua.w << 16), __uint_as_float(ub.w << 16), c2);
      c3 = fmaf(__uint_as_float(ua.w & 0xffff0000u), __uint_as_float(ub.w & 0xffff0000u), c3);
    }
    float v = (c0 + c1) + (c2 + c3);
    int yt = y[(size_t)b * Tq + t];
    float ay = __uint_as_float(((unsigned)eaF[base + yt]) << 16);
    float by = __uint_as_float(((unsigned)eaB[base + yt]) << 16);
    I = (ay * by) / v;
  }
#pragma unroll
  for (int m = 1; m < 64; m <<= 1) I += __shfl_xor(I, m);
  __shared__ float sI[4];
  if ((threadIdx.x & 63) == 0) sI[threadIdx.x >> 6] = I;
  __syncthreads();
  if (threadIdx.x == 0) atomicAdd(&iacc[b], sI[0] + sI[1] + sI[2] + sI[3]);
}

extern "C" __global__ void final_kernel(const float* __restrict__ iacc,
                                        const int* __restrict__ lengths,
                                        float* __restrict__ out) {
  const int b = threadIdx.x;
  if (b < Bq) out[b] = 1.f - (2.f * iacc[b] + 1.f) / (2.f * (float)lengths[b] + 1.f);
}

extern "C" void kernel_launch(void* const* d_in, const int* in_sizes, int n_in,
                              void* d_out, int out_size, void* d_ws, size_t ws_size,
                              hipStream_t stream) {
  const float* pot = (const float*)d_in[0];
  const int* y_true = (const int*)d_in[1];
  const int* lengths = (const int*)d_in[2];
  const float* trans = (const float*)d_in[3];
  float* out = (float*)d_out;

  char* ws = (char*)d_ws;
  const size_t n_elems = (size_t)Bq * Tq * Nq;       // 16,777,216
  u16* eaF = (u16*)ws;                               // 32 MiB
  u16* eaB = (u16*)(ws + n_elems * 2);               // 32 MiB
  float* iacc = (float*)(ws + n_elems * 4);          // 512 B

  crf_chain_kernel<<<Bq * 2 * NSEG / 4, 64, 0, stream>>>(pot, lengths, trans, eaF, eaB, iacc);
  dice_kernel<<<Bq * 16, 256, 0, stream>>>(eaF, eaB, y_true, lengths, iacc);
  final_kernel<<<1, 128, 0, stream>>>(iacc, lengths, out);
}

// Round 6
// 175.505 us; speedup vs baseline: 1.1899x; 1.1899x over previous
//
#include <hip/hip_runtime.h>
#include <hip/hip_bf16.h>

#define Bq 128
#define Tq 4096
#define Nq 32
#define SEGL 32
#define NSEG 128         // Tq / SEGL
#define BURN 12
#define LOG2E 1.4426950408889634f

typedef unsigned short u16;

__device__ __forceinline__ u16 f2bf(float f) {  // RNE f32->bf16
  unsigned u = __float_as_uint(f);
  u = u + 0x7fffu + ((u >> 16) & 1u);
  return (u16)(u >> 16);
}

// Scalar power-of-2 renorm: divide whole vector by 2^(exponent of first lane).
__device__ __forceinline__ void renorm(float& raw) {
  int s0 = __builtin_amdgcn_readfirstlane(__float_as_int(raw));
  int sh = s0 & 0x7f800000;
  float corr = __int_as_float(0x7f000000 - sh);  // 2^{-e}
  raw *= corr;
}

typedef float v4f __attribute__((ext_vector_type(4)));

// Forward: raw_new[j] = (sum_i raw_i * eT[i][j]) * epot[j] (eT col j per lane).
__device__ __forceinline__ void step_fwd(float& raw, const float* B, const float* eT, float epot) {
  float a0 = 0.f, a1 = 0.f, a2 = 0.f, a3 = 0.f;
#pragma unroll
  for (int i = 0; i < 32; i += 4) {
    a0 = fmaf(B[i + 0], eT[i + 0], a0);
    a1 = fmaf(B[i + 1], eT[i + 1], a1);
    a2 = fmaf(B[i + 2], eT[i + 2], a2);
    a3 = fmaf(B[i + 3], eT[i + 3], a3);
  }
  raw = (((a0 + a1) + (a2 + a3))) * epot;
}

// Backward: w already includes epot; raw_new[i] = sum_j w_j * eT[j] (row i per lane).
__device__ __forceinline__ void step_bwd(float& raw, const float* B, const float* eT) {
  float a0 = 0.f, a1 = 0.f, a2 = 0.f, a3 = 0.f;
#pragma unroll
  for (int i = 0; i < 32; i += 4) {
    a0 = fmaf(B[i + 0], eT[i + 0], a0);
    a1 = fmaf(B[i + 1], eT[i + 1], a1);
    a2 = fmaf(B[i + 2], eT[i + 2], a2);
    a3 = fmaf(B[i + 3], eT[i + 3], a3);
  }
  raw = (a0 + a1) + (a2 + a3);
}

// One wave per (batch b, segment s): lanes 0-31 forward, lanes 32-63 backward.
// fp32 state broadcast through LDS (1 ds_write_b32 + 8 ds_read_b128 per step;
// 2-way bank alias between halves = free). Segmented scan with 12-step burn-in
// (Hilbert contraction ~0.38/step -> residual ~2e-5 << bf16 storage noise).
// Rows carry arbitrary power-of-2 scale; dice renormalizes per row.
extern "C" __global__ void __launch_bounds__(64, 4)
crf_chain_kernel(const float* __restrict__ pot, const int* __restrict__ lengths,
                 const float* __restrict__ trans,
                 u16* __restrict__ eaF, u16* __restrict__ eaB,
                 float* __restrict__ iacc) {
  __shared__ v4f sbuf4[16];
  float* sbuf = (float*)sbuf4;
  const int tid = threadIdx.x;
  if (blockIdx.x < 2) iacc[blockIdx.x * 64 + tid] = 0.f;  // zero dice accumulators

  const int j = tid & 31;
  const int half = tid >> 5;           // 0 = fwd, 1 = bwd
  const int b = blockIdx.x >> 7;
  const int s = blockIdx.x & 127;
  const int len = lengths[b];
  const int sL = s * SEGL;
  if (sL >= len) return;
  const int lenm1 = len - 1;
  const int tend = min(sL + SEGL, len);     // exclusive fwd write bound
  const int end = tend - 1;                 // inclusive last row of segment
  const int t1 = min(lenm1, end + BURN);    // bwd init row (beta == 1 there)

  // eT: fwd lane j holds column j of exp(trans); bwd lane i holds row i.
  float eT[32];
#pragma unroll
  for (int i = 0; i < 32; ++i) {
    float tv = half ? trans[j * Nq + i] : trans[i * Nq + j];
    eT[i] = exp2f(tv * LOG2E);
  }

  const float* pb = pot + (size_t)b * Tq * Nq;
  const size_t base = (size_t)b * Tq;
  float B[32];

  if (!half) {
    const int tstart = (s == 0) ? 0 : sL - BURN;   // held row at init
    float raw = exp2f(pb[tstart * Nq + j] * LOG2E);
    if (tstart >= sL) eaF[(base + tstart) * Nq + j] = f2bf(raw);

    int t = tstart + 1;
    float pn[4];
#pragma unroll
    for (int k = 0; k < 4; ++k) { int tt = min(t + k, lenm1); pn[k] = pb[tt * Nq + j]; }
    while (t + 4 <= tend) {
      float pc[4];
#pragma unroll
      for (int k = 0; k < 4; ++k) pc[k] = pn[k];
#pragma unroll
      for (int k = 0; k < 4; ++k) { int tt = min(t + 4 + k, lenm1); pn[k] = pb[tt * Nq + j]; }
      renorm(raw);
#pragma unroll
      for (int k = 0; k < 4; ++k) {
        sbuf[tid] = raw;
#pragma unroll
        for (int q = 0; q < 8; ++q) *(v4f*)&B[q * 4] = sbuf4[q];
        step_fwd(raw, B, eT, exp2f(pc[k] * LOG2E));
        if (t + k >= sL) eaF[(base + t + k) * Nq + j] = f2bf(raw);
      }
      t += 4;
    }
    renorm(raw);
#pragma unroll
    for (int k = 0; k < 4; ++k) {
      if (t + k < tend) {
        sbuf[tid] = raw;
#pragma unroll
        for (int q = 0; q < 8; ++q) *(v4f*)&B[q * 4] = sbuf4[q];
        step_fwd(raw, B, eT, exp2f(pn[k] * LOG2E));
        if (t + k >= sL) eaF[(base + t + k) * Nq + j] = f2bf(raw);
      }
    }
  } else {
    float raw = 1.0f;
    if (t1 <= end) eaB[(base + t1) * Nq + j] = f2bf(1.0f);

    int u = t1;  // consume pot row u to produce beta_{u-1}
    float pn[4];
#pragma unroll
    for (int k = 0; k < 4; ++k) { int tt = max(u - k, 0); pn[k] = pb[tt * Nq + j]; }
    while (u - 4 >= sL) {
      float pc[4];
#pragma unroll
      for (int k = 0; k < 4; ++k) pc[k] = pn[k];
#pragma unroll
      for (int k = 0; k < 4; ++k) { int tt = max(u - 4 - k, 0); pn[k] = pb[tt * Nq + j]; }
      renorm(raw);
#pragma unroll
      for (int k = 0; k < 4; ++k) {
        sbuf[tid] = raw * exp2f(pc[k] * LOG2E);
#pragma unroll
        for (int q = 0; q < 8; ++q) *(v4f*)&B[q * 4] = sbuf4[8 + q];
        step_bwd(raw, B, eT);
        int tw = u - 1 - k;
        if (tw <= end) eaB[(base + tw) * Nq + j] = f2bf(raw);
      }
      u -= 4;
    }
    renorm(raw);
    const int rem = u - sL;  // 0..3 steps remain
#pragma unroll
    for (int k = 0; k < 4; ++k) {
      if (k < rem) {
        sbuf[tid] = raw * exp2f(pn[k] * LOG2E);
#pragma unroll
        for (int q = 0; q < 8; ++q) *(v4f*)&B[q * 4] = sbuf4[8 + q];
        step_bwd(raw, B, eT);
        int tw = u - 1 - k;
        if (tw <= end) eaB[(base + tw) * Nq + j] = f2bf(raw);
      }
    }
  }
}

// One THREAD per position; 2048 blocks. p_t[y]/sum via per-row normalization.
extern "C" __global__ void __launch_bounds__(256)
dice_kernel(const u16* __restrict__ eaF, const u16* __restrict__ eaB,
            const int* __restrict__ y, const int* __restrict__ lengths,
            float* __restrict__ iacc) {
  const int b = blockIdx.x >> 4;
  const int q = blockIdx.x & 15;
  const int len = lengths[b];
  if (q * 256 >= len) return;
  const int t = q * 256 + threadIdx.x;
  float I = 0.f;
  if (t < len) {
    const size_t base = ((size_t)b * Tq + t) * Nq;
    const uint4* a4 = (const uint4*)(eaF + base);
    const uint4* b4 = (const uint4*)(eaB + base);
    float c0 = 0.f, c1 = 0.f, c2 = 0.f, c3 = 0.f;
#pragma unroll
    for (int w = 0; w < 4; ++w) {
      uint4 ua = a4[w], ub = b4[w];
      c0 = fmaf(__uint_as_float(ua.x << 16), __uint_as_float(ub.x << 16), c0);
      c1 = fmaf(__uint_as_float(ua.x & 0xffff0000u), __uint_as_float(ub.x & 0xffff0000u), c1);
      c2 = fmaf(__uint_as_float(ua.y << 16), __uint_as_float(ub.y << 16), c2);
      c3 = fmaf(__uint_as_float(ua.y & 0xffff0000u), __uint_as_float(ub.y & 0xffff0000u), c3);
      c0 = fmaf(__uint_as_float(ua.z << 16), __uint_as_float(ub.z << 16), c0);
      c1 = fmaf(__uint_as_float(ua.z & 0xffff0000u), __uint_as_float(ub.z & 0xffff0000u), c1);
      c2 = fmaf(__uint_as_float(ua.w << 16), __uint_as_float(ub.w << 16), c2);
      c3 = fmaf(__uint_as_float(ua.w & 0xffff0000u), __uint_as_float(ub.w & 0xffff0000u), c3);
    }
    float v = (c0 + c1) + (c2 + c3);
    int yt = y[(size_t)b * Tq + t];
    float ay = __uint_as_float(((unsigned)eaF[base + yt]) << 16);
    float by = __uint_as_float(((unsigned)eaB[base + yt]) << 16);
    I = (ay * by) / v;
  }
#pragma unroll
  for (int m = 1; m < 64; m <<= 1) I += __shfl_xor(I, m);
  __shared__ float sI[4];
  if ((threadIdx.x & 63) == 0) sI[threadIdx.x >> 6] = I;
  __syncthreads();
  if (threadIdx.x == 0) atomicAdd(&iacc[b], sI[0] + sI[1] + sI[2] + sI[3]);
}

extern "C" __global__ void final_kernel(const float* __restrict__ iacc,
                                        const int* __restrict__ lengths,
                                        float* __restrict__ out) {
  const int b = threadIdx.x;
  if (b < Bq) out[b] = 1.f - (2.f * iacc[b] + 1.f) / (2.f * (float)lengths[b] + 1.f);
}

extern "C" void kernel_launch(void* const* d_in, const int* in_sizes, int n_in,
                              void* d_out, int out_size, void* d_ws, size_t ws_size,
                              hipStream_t stream) {
  const float* pot = (const float*)d_in[0];
  const int* y_true = (const int*)d_in[1];
  const int* lengths = (const int*)d_in[2];
  const float* trans = (const float*)d_in[3];
  float* out = (float*)d_out;

  char* ws = (char*)d_ws;
  const size_t n_elems = (size_t)Bq * Tq * Nq;       // 16,777,216
  u16* eaF = (u16*)ws;                               // 32 MiB
  u16* eaB = (u16*)(ws + n_elems * 2);               // 32 MiB
  float* iacc = (float*)(ws + n_elems * 4);          // 512 B

  crf_chain_kernel<<<Bq * NSEG, 64, 0, stream>>>(pot, lengths, trans, eaF, eaB, iacc);
  dice_kernel<<<Bq * 16, 256, 0, stream>>>(eaF, eaB, y_true, lengths, iacc);
  final_kernel<<<1, 128, 0, stream>>>(iacc, lengths, out);
}